// Round 8
// baseline (1438.671 us; speedup 1.0000x reference)
//
#include <hip/hip_runtime.h>

// Muskingum-Cunge routing on a full binary tree (heap layout), depth 13.
// N = 8191 reaches, T = 2048 timesteps. Outlet = node 0.
// Round 8: force the load burst with value-anchoring volatile asm.
//   R7 falsified the sched_barrier approach: VGPR stayed 76 -> LLVM sank each
//   load (incl. relaxed atomic loads) next to its use at IR level; each t pays
//   one IF$ round-trip (~0.19us/t = the measured C(B) slope). Fix: after each
//   load, asm volatile("" : "+v"(x)) pins the value live in a VGPR at that
//   program point -> all 96 loads issue as one pipelined burst.
//   39 blocks (L12 x16 ... L0 x1), per-wave flags, FBATCH=32,
//   __launch_bounds__(256,1).
// Fallback: single-WG kernel (round-1 structure, verified) if ws too small.

#define NN 8191
#define TT 2048
#define FBATCH 32
#define NBLK 39
#define BTHREADS 256

#define FLAGS_FOFF 16773120ull            // float offset of flags (unused L0 buf slot)
#define REQ_BYTES  67106816ull            // proven available in rounds 2-7
#define FLAG_STRIDE 16                    // u32 stride between (block,wave) flags

#if __has_builtin(__builtin_amdgcn_exp2f)
__device__ __forceinline__ float fexp2(float x) { return __builtin_amdgcn_exp2f(x); }
#else
__device__ __forceinline__ float fexp2(float x) { return exp2f(x); }
#endif
#if __has_builtin(__builtin_amdgcn_logf)
__device__ __forceinline__ float flog2(float x) { return __builtin_amdgcn_logf(x); }
#else
__device__ __forceinline__ float flog2(float x) { return log2f(x); }
#endif
#if __has_builtin(__builtin_amdgcn_rcpf)
__device__ __forceinline__ float frcp(float x) { return __builtin_amdgcn_rcpf(x); }
#else
__device__ __forceinline__ float frcp(float x) { return 1.0f / x; }
#endif

// Pin a value live in a VGPR at this program point; volatile asm is unmovable,
// so the producing load cannot sink below it and the value stays resident.
#define PIN(x) asm volatile("" : "+v"(x))

// ---------------- stage tables (39 blocks) ----------------
__constant__ int g_level[NBLK] = {
    12,12,12,12,12,12,12,12,12,12,12,12,12,12,12,12,
    11,11,11,11,11,11,11,11,
    10,10,10,10,
    9,9,
    8,7,6,5,4,3,2,1,0};
__constant__ int g_cnt[NBLK] = {
    256,256,256,256,256,256,256,256,256,256,256,256,256,256,256,256,
    256,256,256,256,256,256,256,256,
    256,256,256,256,
    256,256,
    256,128,64,32,16,8,4,2,1};
// first block id of each level (level 0..12)
__constant__ int g_first[13] = {38,37,36,35,34,33,32,31,30,28,24,16,0};
// float offset of level-l output buffer inside ws (levels 0..12; level 0 unused)
__constant__ unsigned long long g_off[13] = {
    16773120ull, 16769024ull, 16760832ull, 16744448ull, 16711680ull,
    16646144ull, 16515072ull, 16252928ull, 15728640ull, 14680064ull,
    12582912ull, 8388608ull, 0ull};

__device__ __forceinline__ void waitflags(const unsigned int* fa, const unsigned int* fb,
                                          unsigned int target)
{
    while (true) {
        unsigned int a = __hip_atomic_load(fa, __ATOMIC_RELAXED, __HIP_MEMORY_SCOPE_AGENT);
        unsigned int b = fb ? __hip_atomic_load(fb, __ATOMIC_RELAXED, __HIP_MEMORY_SCOPE_AGENT)
                            : a;
        if (a >= target && b >= target) break;
        __builtin_amdgcn_s_sleep(1);
    }
    // Keep subsequent coherent loads from being hoisted above the poll.
    __builtin_amdgcn_sched_barrier(0);
    asm volatile("" ::: "memory");
}

__global__ void zero_flags(unsigned int* flags)
{
    for (int i = threadIdx.x; i < NBLK * 4 * FLAG_STRIDE; i += 256) flags[i] = 0;
}

__global__ __launch_bounds__(BTHREADS, 1)
void pipe_kernel(const float* __restrict__ lat,
                 const float* __restrict__ nman,
                 const float* __restrict__ len,
                 const float* __restrict__ slp,
                 const float* __restrict__ wcf,
                 const float* __restrict__ wex,
                 const float* __restrict__ dcf,
                 const float* __restrict__ dex,
                 const int*   __restrict__ dtp,
                 float*       __restrict__ out,
                 float*       __restrict__ ws)
{
    const int bid = blockIdx.x;
    const int tid = threadIdx.x;
    const int lvl = g_level[bid];
    const int cnt = g_cnt[bid];
    const int W   = tid >> 6;            // wave id within block
    const int wn  = cnt - W * 64;        // active lanes in this wave
    if (wn <= 0) return;                 // shed fully-inactive waves

    const bool active = (tid < cnt);
    const int B = bid - g_first[lvl];                  // block index within level
    const int m = B * 256 + (active ? tid : 0);        // level-local node index
    const int node = ((1 << lvl) - 1) + m;             // heap index
    const int wbase = B * 256 + W * 64;                // wave's first level-local node

    unsigned int* flags = (unsigned int*)(ws + FLAGS_FOFF);
    unsigned int* myflag = flags + ((size_t)bid * 4 + W) * FLAG_STRIDE;

    // producer-wave flags covering this wave's children (round-5, verified)
    const bool haschild = (lvl < 12);
    const unsigned int* fa = nullptr;
    const unsigned int* fb = nullptr;
    if (haschild) {
        const int Fp = g_first[lvl + 1];
        const int nw = wn < 64 ? wn : 64;
        const int p0 = (2 * wbase) >> 6;
        const int p1 = (2 * wbase + 2 * nw - 1) >> 6;
        fa = flags + ((size_t)(Fp + (p0 >> 2)) * 4 + (p0 & 3)) * FLAG_STRIDE;
        fb = (p1 != p0)
           ? flags + ((size_t)(Fp + (p1 >> 2)) * 4 + (p1 & 3)) * FLAG_STRIDE
           : nullptr;
    }

    const int myW = 1 << lvl;
    const int childW = 1 << (lvl + 1);
    float* myBuf = ws + g_off[lvl];
    const unsigned long long* childBuf =
        haschild ? (const unsigned long long*)(ws + g_off[lvl + 1]) : nullptr;

    const float dtf = (float)dtp[0];

    // per-node derived constants + state (registers, persistent)
    //   em  = -(2/3)de ; tkc = 2L/cc ; ex = 1 - we - (2/3)de ; k1 = 0.5/(S L wc cc)
    float em, tkc, ex, k1;
    float Iold = 0.0f, Oold = 0.0f;
    {
        float n = nman[node], L = len[node], S = slp[node];
        float wc = wcf[node], we = wex[node], dc = dcf[node], de = dex[node];
        float dc23 = fexp2(0.6666667f * flog2(dc));
        float cc = 1.6666667f * dc23 * sqrtf(S) * frcp(n);
        float e23 = 0.6666667f * de;
        em  = -e23;
        tkc = 2.0f * L * frcp(cc);
        ex  = 1.0f - we - e23;
        k1  = 0.5f * frcp(S * L * wc * cc);
    }

    float la[FBATCH], c0[FBATCH], c1[FBATCH];

    for (int t0 = 0; t0 < TT; t0 += FBATCH) {
        // ---- lat burst (flag-independent): issue + pin BEFORE the poll so the
        // HBM latency hides under the wait.
        if (active) {
#pragma unroll
            for (int k = 0; k < FBATCH; ++k) {
                la[k] = lat[(size_t)(t0 + k) * NN + node];
                PIN(la[k]);
            }
        }

        if (haschild) waitflags(fa, fb, (unsigned int)(t0 + FBATCH));

        // ---- child burst: 32 coherent 8B loads issued back-to-back, pinned.
        if (haschild && active) {
#pragma unroll
            for (int k = 0; k < FBATCH; ++k) {
                unsigned long long cv = __hip_atomic_load(
                    childBuf + ((size_t)(t0 + k) * childW >> 1) + m,
                    __ATOMIC_RELAXED, __HIP_MEMORY_SCOPE_AGENT);
                float2 c = *(float2*)&cv;
                c0[k] = c.x; c1[k] = c.y;
                PIN(c0[k]); PIN(c1[k]);
            }
        }
        __builtin_amdgcn_sched_barrier(0);

        // ---- serial compute chain + coherent stores
        if (active) {
#pragma unroll
            for (int k = 0; k < FBATCH; ++k) {
                float Inew = la[k] + (haschild ? (c0[k] + c1[k]) : 0.0f);
                float Qr = fmaxf(0.5f * (Inew + Oold), 1e-3f);
                float lg = flog2(Qr);
                float twoK = tkc * fexp2(em * lg);
                float X = fmaxf(0.5f - k1 * fexp2(ex * lg), 0.0f);
                float A = twoK * X;
                float Bv = twoK - A;
                float r = frcp(Bv + dtf);
                float num = dtf * (Inew + Iold - Oold) + A * (Iold - Inew) + Bv * Oold;
                float O = fmaxf(num * r, 0.0f);
                Iold = Inew; Oold = O;
                if (lvl > 0)
                    __hip_atomic_store(myBuf + (size_t)(t0 + k) * myW + m, O,
                                       __ATOMIC_RELAXED, __HIP_MEMORY_SCOPE_AGENT);
                else
                    out[t0 + k] = O;
            }
        }

        if (lvl > 0) {
            // per-wave publish: stores acked at coherency point, then flag.
            asm volatile("s_waitcnt vmcnt(0)" ::: "memory");
            if ((tid & 63) == 0)
                __hip_atomic_store(myflag, (unsigned int)(t0 + FBATCH),
                                   __ATOMIC_RELAXED, __HIP_MEMORY_SCOPE_AGENT);
        }
    }
}

// ---------------- fallback: single-WG kernel (round-1 structure, verified) ----
#define NTHREADS 1024
__device__ __forceinline__ float mc_update_fb(float Inew, float Iold, float Oold,
                                              float em, float tkc, float ex, float k1,
                                              float dtf)
{
    float Qr = fmaxf(0.5f * (Inew + Oold), 1e-3f);
    float lg = flog2(Qr);
    float twoK = tkc * fexp2(em * lg);
    float X = fmaxf(0.5f - k1 * fexp2(ex * lg), 0.0f);
    float A = twoK * X;
    float B = twoK - A;
    float r = frcp(B + dtf);
    float C1 = (dtf - A) * r;
    float C2 = (dtf + A) * r;
    float C3 = (B - dtf) * r;
    return fmaxf(C1 * Inew + C2 * Iold + C3 * Oold, 0.0f);
}

__global__ __launch_bounds__(NTHREADS)
void route_kernel(const float* __restrict__ lat,
                  const float* __restrict__ nman,
                  const float* __restrict__ len,
                  const float* __restrict__ slp,
                  const float* __restrict__ wcf,
                  const float* __restrict__ wex,
                  const float* __restrict__ dcf,
                  const float* __restrict__ dex,
                  const int*   __restrict__ dtp,
                  float*       __restrict__ out)
{
    __shared__ float Osh[NN];
    const int tid = threadIdx.x;
    const float dtf = (float)dtp[0];

    int nodes[8];
    nodes[0] = 4095 + tid;
    nodes[1] = 5119 + tid;
    nodes[2] = 6143 + tid;
    nodes[3] = 7167 + tid;
    nodes[4] = 2047 + tid;
    nodes[5] = 3071 + tid;
    nodes[6] = 1023 + tid;
    nodes[7] = (tid < 1023) ? tid : 0;

    float em[8], tkc[8], ex[8], k1[8];
    float Ireg[8], Oreg[8];
#pragma unroll
    for (int k = 0; k < 8; ++k) {
        int i = nodes[k];
        float n = nman[i], L = len[i], S = slp[i];
        float wc = wcf[i], we = wex[i], dc = dcf[i], de = dex[i];
        float dc23 = fexp2(0.6666667f * flog2(dc));
        float cc = 1.6666667f * dc23 * sqrtf(S) * frcp(n);
        float e23 = 0.6666667f * de;
        em[k]  = -e23;
        tkc[k] = 2.0f * L * frcp(cc);
        ex[k]  = 1.0f - we - e23;
        k1[k]  = 0.5f * frcp(S * L * wc * cc);
        Ireg[k] = 0.0f; Oreg[k] = 0.0f;
    }
    for (int i = tid; i < NN; i += NTHREADS) Osh[i] = 0.0f;
    __syncthreads();

    for (int t = 0; t < TT; ++t) {
        const float* __restrict__ latt = lat + (size_t)t * NN;
#pragma unroll
        for (int k = 0; k < 4; ++k) {
            int i = nodes[k];
            float Inew = latt[i];
            float O = mc_update_fb(Inew, Ireg[k], Oreg[k], em[k], tkc[k], ex[k], k1[k], dtf);
            Ireg[k] = Inew; Oreg[k] = O; Osh[i] = O;
        }
        __syncthreads();
#pragma unroll
        for (int k = 4; k < 6; ++k) {
            int i = nodes[k];
            float Inew = latt[i] + Osh[2 * i + 1] + Osh[2 * i + 2];
            float O = mc_update_fb(Inew, Ireg[k], Oreg[k], em[k], tkc[k], ex[k], k1[k], dtf);
            Ireg[k] = Inew; Oreg[k] = O; Osh[i] = O;
        }
        __syncthreads();
        {
            int i = nodes[6];
            float Inew = latt[i] + Osh[2 * i + 1] + Osh[2 * i + 2];
            float O = mc_update_fb(Inew, Ireg[6], Oreg[6], em[6], tkc[6], ex[6], k1[6], dtf);
            Ireg[6] = Inew; Oreg[6] = O; Osh[i] = O;
        }
        __syncthreads();
        for (int l = 9; l >= 0; --l) {
            int s = (1 << l) - 1;
            int e = (1 << (l + 1)) - 1;
            if (tid >= s && tid < e) {
                int i = tid;
                float Inew = latt[i] + Osh[2 * i + 1] + Osh[2 * i + 2];
                float O = mc_update_fb(Inew, Ireg[7], Oreg[7], em[7], tkc[7], ex[7], k1[7], dtf);
                Ireg[7] = Inew; Oreg[7] = O; Osh[i] = O;
            }
            __syncthreads();
        }
        if (tid == 0) out[t] = Oreg[7];
    }
}

extern "C" void kernel_launch(void* const* d_in, const int* in_sizes, int n_in,
                              void* d_out, int out_size, void* d_ws, size_t ws_size,
                              hipStream_t stream) {
    const float* lat  = (const float*)d_in[0];
    const float* nman = (const float*)d_in[1];
    const float* len  = (const float*)d_in[2];
    const float* slp  = (const float*)d_in[3];
    const float* wcf  = (const float*)d_in[4];
    const float* wex  = (const float*)d_in[5];
    const float* dcf  = (const float*)d_in[6];
    const float* dex  = (const float*)d_in[7];
    const int*   dtp  = (const int*)d_in[8];
    float* out = (float*)d_out;

    if (ws_size >= REQ_BYTES) {
        float* ws = (float*)d_ws;
        unsigned int* flags = (unsigned int*)(ws + FLAGS_FOFF);
        zero_flags<<<dim3(1), dim3(256), 0, stream>>>(flags);
        pipe_kernel<<<dim3(NBLK), dim3(BTHREADS), 0, stream>>>(
            lat, nman, len, slp, wcf, wex, dcf, dex, dtp, out, ws);
    } else {
        route_kernel<<<dim3(1), dim3(NTHREADS), 0, stream>>>(
            lat, nman, len, slp, wcf, wex, dcf, dex, dtp, out);
    }
}

// Round 9
// 404.049 us; speedup vs baseline: 3.5606x; 3.5606x over previous
//
#include <hip/hip_runtime.h>

// Muskingum-Cunge routing on a full binary tree (heap layout), depth 13.
// N = 8191 reaches, T = 2048 timesteps. Outlet = node 0.
// Round 9: inline-asm load bursts.
//   R4-R8 diagnosis: C(B) ∝ B, slope = one IF$/HBM round-trip per timestep.
//   C-level loads (atomic or plain) get sunk to their uses (VGPR stuck at 76),
//   serializing one latency per t. R8's per-value PIN forced a waitcnt per
//   load (3x worse). Fix: issue the 32 lat + 32 child loads as volatile
//   inline-asm global_load bursts -> back-to-back issue, no intermediate
//   waitcnts, results pinned live by "=v" outputs; ONE manual
//   s_waitcnt vmcnt(0) + sched_barrier(0) before the serial chain.
//   39 blocks (L12 x16 ... L0 x1), per-wave flags, FBATCH=32,
//   __launch_bounds__(256,1).
// Fallback: single-WG kernel (round-1 structure, verified) if ws too small.

#define NN 8191
#define TT 2048
#define FBATCH 32
#define NBLK 39
#define BTHREADS 256

#define FLAGS_FOFF 16773120ull            // float offset of flags (unused L0 buf slot)
#define REQ_BYTES  67106816ull            // proven available in rounds 2-8
#define FLAG_STRIDE 16                    // u32 stride between (block,wave) flags

#if __has_builtin(__builtin_amdgcn_exp2f)
__device__ __forceinline__ float fexp2(float x) { return __builtin_amdgcn_exp2f(x); }
#else
__device__ __forceinline__ float fexp2(float x) { return exp2f(x); }
#endif
#if __has_builtin(__builtin_amdgcn_logf)
__device__ __forceinline__ float flog2(float x) { return __builtin_amdgcn_logf(x); }
#else
__device__ __forceinline__ float flog2(float x) { return log2f(x); }
#endif
#if __has_builtin(__builtin_amdgcn_rcpf)
__device__ __forceinline__ float frcp(float x) { return __builtin_amdgcn_rcpf(x); }
#else
__device__ __forceinline__ float frcp(float x) { return 1.0f / x; }
#endif

// ---------------- stage tables (39 blocks) ----------------
__constant__ int g_level[NBLK] = {
    12,12,12,12,12,12,12,12,12,12,12,12,12,12,12,12,
    11,11,11,11,11,11,11,11,
    10,10,10,10,
    9,9,
    8,7,6,5,4,3,2,1,0};
__constant__ int g_cnt[NBLK] = {
    256,256,256,256,256,256,256,256,256,256,256,256,256,256,256,256,
    256,256,256,256,256,256,256,256,
    256,256,256,256,
    256,256,
    256,128,64,32,16,8,4,2,1};
// first block id of each level (level 0..12)
__constant__ int g_first[13] = {38,37,36,35,34,33,32,31,30,28,24,16,0};
// float offset of level-l output buffer inside ws (levels 0..12; level 0 unused)
__constant__ unsigned long long g_off[13] = {
    16773120ull, 16769024ull, 16760832ull, 16744448ull, 16711680ull,
    16646144ull, 16515072ull, 16252928ull, 15728640ull, 14680064ull,
    12582912ull, 8388608ull, 0ull};

__device__ __forceinline__ void waitflags(const unsigned int* fa, const unsigned int* fb,
                                          unsigned int target)
{
    while (true) {
        unsigned int a = __hip_atomic_load(fa, __ATOMIC_RELAXED, __HIP_MEMORY_SCOPE_AGENT);
        unsigned int b = fb ? __hip_atomic_load(fb, __ATOMIC_RELAXED, __HIP_MEMORY_SCOPE_AGENT)
                            : a;
        if (a >= target && b >= target) break;
        __builtin_amdgcn_s_sleep(1);
    }
    // Keep subsequent coherent loads from being hoisted above the poll.
    __builtin_amdgcn_sched_barrier(0);
    asm volatile("" ::: "memory");
}

__global__ void zero_flags(unsigned int* flags)
{
    for (int i = threadIdx.x; i < NBLK * 4 * FLAG_STRIDE; i += 256) flags[i] = 0;
}

__global__ __launch_bounds__(BTHREADS, 1)
void pipe_kernel(const float* __restrict__ lat,
                 const float* __restrict__ nman,
                 const float* __restrict__ len,
                 const float* __restrict__ slp,
                 const float* __restrict__ wcf,
                 const float* __restrict__ wex,
                 const float* __restrict__ dcf,
                 const float* __restrict__ dex,
                 const int*   __restrict__ dtp,
                 float*       __restrict__ out,
                 float*       __restrict__ ws)
{
    const int bid = blockIdx.x;
    const int tid = threadIdx.x;
    const int lvl = g_level[bid];
    const int cnt = g_cnt[bid];
    const int W   = tid >> 6;            // wave id within block
    const int wn  = cnt - W * 64;        // active lanes in this wave
    if (wn <= 0) return;                 // shed fully-inactive waves

    const bool active = (tid < cnt);
    const int B = bid - g_first[lvl];                  // block index within level
    const int m = B * 256 + (active ? tid : 0);        // level-local node index
    const int node = ((1 << lvl) - 1) + m;             // heap index
    const int wbase = B * 256 + W * 64;                // wave's first level-local node

    unsigned int* flags = (unsigned int*)(ws + FLAGS_FOFF);
    unsigned int* myflag = flags + ((size_t)bid * 4 + W) * FLAG_STRIDE;

    // producer-wave flags covering this wave's children (round-5, verified)
    const bool haschild = (lvl < 12);
    const unsigned int* fa = nullptr;
    const unsigned int* fb = nullptr;
    if (haschild) {
        const int Fp = g_first[lvl + 1];
        const int nw = wn < 64 ? wn : 64;
        const int p0 = (2 * wbase) >> 6;
        const int p1 = (2 * wbase + 2 * nw - 1) >> 6;
        fa = flags + ((size_t)(Fp + (p0 >> 2)) * 4 + (p0 & 3)) * FLAG_STRIDE;
        fb = (p1 != p0)
           ? flags + ((size_t)(Fp + (p1 >> 2)) * 4 + (p1 & 3)) * FLAG_STRIDE
           : nullptr;
    }

    const int myW = 1 << lvl;
    const int childW = 1 << (lvl + 1);
    float* myBuf = ws + g_off[lvl];
    const unsigned long long* childBuf =
        haschild ? (const unsigned long long*)(ws + g_off[lvl + 1]) : nullptr;

    const float dtf = (float)dtp[0];

    // per-node derived constants + state (registers, persistent)
    //   em  = -(2/3)de ; tkc = 2L/cc ; ex = 1 - we - (2/3)de ; k1 = 0.5/(S L wc cc)
    float em, tkc, ex, k1;
    float Iold = 0.0f, Oold = 0.0f;
    {
        float n = nman[node], L = len[node], S = slp[node];
        float wc = wcf[node], we = wex[node], dc = dcf[node], de = dex[node];
        float dc23 = fexp2(0.6666667f * flog2(dc));
        float cc = 1.6666667f * dc23 * sqrtf(S) * frcp(n);
        float e23 = 0.6666667f * de;
        em  = -e23;
        tkc = 2.0f * L * frcp(cc);
        ex  = 1.0f - we - e23;
        k1  = 0.5f * frcp(S * L * wc * cc);
    }

    float la[FBATCH];
    unsigned long long cv[FBATCH];

    for (int t0 = 0; t0 < TT; t0 += FBATCH) {
        // ---- lat burst (flag-independent): 32 plain global_load_dword issued
        // back-to-back via volatile asm (no intermediate waitcnts, results
        // pinned live). Latency overlaps the poll below.
        if (active) {
#pragma unroll
            for (int k = 0; k < FBATCH; ++k) {
                const float* lp = lat + (size_t)(t0 + k) * NN + node;
                asm volatile("global_load_dword %0, %1, off"
                             : "=v"(la[k]) : "v"(lp));
            }
        }

        if (haschild) waitflags(fa, fb, (unsigned int)(t0 + FBATCH));

        // ---- child burst: 32 coherent 8B loads (sc0 sc1 -> serviced at IF$,
        // same semantics as the verified __hip_atomic_load AGENT path).
        if (haschild && active) {
#pragma unroll
            for (int k = 0; k < FBATCH; ++k) {
                const unsigned long long* cp =
                    childBuf + (((size_t)(t0 + k) * childW) >> 1) + m;
                asm volatile("global_load_dwordx2 %0, %1, off sc0 sc1"
                             : "=v"(cv[k]) : "v"(cp));
            }
        }

        // ONE wait for the whole burst, then pin program order (rule #18).
        asm volatile("s_waitcnt vmcnt(0)" ::: "memory");
        __builtin_amdgcn_sched_barrier(0);

        // ---- serial compute chain + coherent stores
        if (active) {
#pragma unroll
            for (int k = 0; k < FBATCH; ++k) {
                float ch = 0.0f;
                if (haschild) {
                    float c0 = __uint_as_float((unsigned int)(cv[k] & 0xffffffffull));
                    float c1 = __uint_as_float((unsigned int)(cv[k] >> 32));
                    ch = c0 + c1;
                }
                float Inew = la[k] + ch;
                float Qr = fmaxf(0.5f * (Inew + Oold), 1e-3f);
                float lg = flog2(Qr);
                float twoK = tkc * fexp2(em * lg);
                float X = fmaxf(0.5f - k1 * fexp2(ex * lg), 0.0f);
                float A = twoK * X;
                float Bv = twoK - A;
                float r = frcp(Bv + dtf);
                float num = dtf * (Inew + Iold - Oold) + A * (Iold - Inew) + Bv * Oold;
                float O = fmaxf(num * r, 0.0f);
                Iold = Inew; Oold = O;
                if (lvl > 0)
                    __hip_atomic_store(myBuf + (size_t)(t0 + k) * myW + m, O,
                                       __ATOMIC_RELAXED, __HIP_MEMORY_SCOPE_AGENT);
                else
                    out[t0 + k] = O;
            }
        }

        if (lvl > 0) {
            // per-wave publish: stores acked at coherency point, then flag.
            asm volatile("s_waitcnt vmcnt(0)" ::: "memory");
            if ((tid & 63) == 0)
                __hip_atomic_store(myflag, (unsigned int)(t0 + FBATCH),
                                   __ATOMIC_RELAXED, __HIP_MEMORY_SCOPE_AGENT);
        }
    }
}

// ---------------- fallback: single-WG kernel (round-1 structure, verified) ----
#define NTHREADS 1024
__device__ __forceinline__ float mc_update_fb(float Inew, float Iold, float Oold,
                                              float em, float tkc, float ex, float k1,
                                              float dtf)
{
    float Qr = fmaxf(0.5f * (Inew + Oold), 1e-3f);
    float lg = flog2(Qr);
    float twoK = tkc * fexp2(em * lg);
    float X = fmaxf(0.5f - k1 * fexp2(ex * lg), 0.0f);
    float A = twoK * X;
    float B = twoK - A;
    float r = frcp(B + dtf);
    float C1 = (dtf - A) * r;
    float C2 = (dtf + A) * r;
    float C3 = (B - dtf) * r;
    return fmaxf(C1 * Inew + C2 * Iold + C3 * Oold, 0.0f);
}

__global__ __launch_bounds__(NTHREADS)
void route_kernel(const float* __restrict__ lat,
                  const float* __restrict__ nman,
                  const float* __restrict__ len,
                  const float* __restrict__ slp,
                  const float* __restrict__ wcf,
                  const float* __restrict__ wex,
                  const float* __restrict__ dcf,
                  const float* __restrict__ dex,
                  const int*   __restrict__ dtp,
                  float*       __restrict__ out)
{
    __shared__ float Osh[NN];
    const int tid = threadIdx.x;
    const float dtf = (float)dtp[0];

    int nodes[8];
    nodes[0] = 4095 + tid;
    nodes[1] = 5119 + tid;
    nodes[2] = 6143 + tid;
    nodes[3] = 7167 + tid;
    nodes[4] = 2047 + tid;
    nodes[5] = 3071 + tid;
    nodes[6] = 1023 + tid;
    nodes[7] = (tid < 1023) ? tid : 0;

    float em[8], tkc[8], ex[8], k1[8];
    float Ireg[8], Oreg[8];
#pragma unroll
    for (int k = 0; k < 8; ++k) {
        int i = nodes[k];
        float n = nman[i], L = len[i], S = slp[i];
        float wc = wcf[i], we = wex[i], dc = dcf[i], de = dex[i];
        float dc23 = fexp2(0.6666667f * flog2(dc));
        float cc = 1.6666667f * dc23 * sqrtf(S) * frcp(n);
        float e23 = 0.6666667f * de;
        em[k]  = -e23;
        tkc[k] = 2.0f * L * frcp(cc);
        ex[k]  = 1.0f - we - e23;
        k1[k]  = 0.5f * frcp(S * L * wc * cc);
        Ireg[k] = 0.0f; Oreg[k] = 0.0f;
    }
    for (int i = tid; i < NN; i += NTHREADS) Osh[i] = 0.0f;
    __syncthreads();

    for (int t = 0; t < TT; ++t) {
        const float* __restrict__ latt = lat + (size_t)t * NN;
#pragma unroll
        for (int k = 0; k < 4; ++k) {
            int i = nodes[k];
            float Inew = latt[i];
            float O = mc_update_fb(Inew, Ireg[k], Oreg[k], em[k], tkc[k], ex[k], k1[k], dtf);
            Ireg[k] = Inew; Oreg[k] = O; Osh[i] = O;
        }
        __syncthreads();
#pragma unroll
        for (int k = 4; k < 6; ++k) {
            int i = nodes[k];
            float Inew = latt[i] + Osh[2 * i + 1] + Osh[2 * i + 2];
            float O = mc_update_fb(Inew, Ireg[k], Oreg[k], em[k], tkc[k], ex[k], k1[k], dtf);
            Ireg[k] = Inew; Oreg[k] = O; Osh[i] = O;
        }
        __syncthreads();
        {
            int i = nodes[6];
            float Inew = latt[i] + Osh[2 * i + 1] + Osh[2 * i + 2];
            float O = mc_update_fb(Inew, Ireg[6], Oreg[6], em[6], tkc[6], ex[6], k1[6], dtf);
            Ireg[6] = Inew; Oreg[6] = O; Osh[i] = O;
        }
        __syncthreads();
        for (int l = 9; l >= 0; --l) {
            int s = (1 << l) - 1;
            int e = (1 << (l + 1)) - 1;
            if (tid >= s && tid < e) {
                int i = tid;
                float Inew = latt[i] + Osh[2 * i + 1] + Osh[2 * i + 2];
                float O = mc_update_fb(Inew, Ireg[7], Oreg[7], em[7], tkc[7], ex[7], k1[7], dtf);
                Ireg[7] = Inew; Oreg[7] = O; Osh[i] = O;
            }
            __syncthreads();
        }
        if (tid == 0) out[t] = Oreg[7];
    }
}

extern "C" void kernel_launch(void* const* d_in, const int* in_sizes, int n_in,
                              void* d_out, int out_size, void* d_ws, size_t ws_size,
                              hipStream_t stream) {
    const float* lat  = (const float*)d_in[0];
    const float* nman = (const float*)d_in[1];
    const float* len  = (const float*)d_in[2];
    const float* slp  = (const float*)d_in[3];
    const float* wcf  = (const float*)d_in[4];
    const float* wex  = (const float*)d_in[5];
    const float* dcf  = (const float*)d_in[6];
    const float* dex  = (const float*)d_in[7];
    const int*   dtp  = (const int*)d_in[8];
    float* out = (float*)d_out;

    if (ws_size >= REQ_BYTES) {
        float* ws = (float*)d_ws;
        unsigned int* flags = (unsigned int*)(ws + FLAGS_FOFF);
        zero_flags<<<dim3(1), dim3(256), 0, stream>>>(flags);
        pipe_kernel<<<dim3(NBLK), dim3(BTHREADS), 0, stream>>>(
            lat, nman, len, slp, wcf, wex, dcf, dex, dtp, out, ws);
    } else {
        route_kernel<<<dim3(1), dim3(NTHREADS), 0, stream>>>(
            lat, nman, len, slp, wcf, wex, dcf, dex, dtp, out);
    }
}